// Round 10
// baseline (303.148 us; speedup 1.0000x reference)
//
#include <hip/hip_runtime.h>

#define HH 16
#define SS 4096
#define DHD 128
#define BR 64         // q rows per block (16 per wave)
#define BC 64         // k/v rows per tile
#define LDQS 136      // bf16/row for Q staging (prologue only)
#define LDQ 144       // fallback kernel k_s stride (R0-measured-good)
#define LDV 68        // fallback kernel vt_s stride
#define LDPT 72       // bf16/row for pT_s: 144B (16B-aligned)
#define LDOS 136      // f32/row for epilogue overlay
#define DM  (HH * DHD)

typedef __bf16 bf16x8_t __attribute__((ext_vector_type(8)));
typedef __bf16 bf16x4_t __attribute__((ext_vector_type(4)));
typedef float  f32x4_t  __attribute__((ext_vector_type(4)));

// lgkm-drain barrier (fallback kernel only)
#define BAR()  asm volatile("s_waitcnt lgkmcnt(0)\n\ts_barrier" ::: "memory")

__device__ __forceinline__ f32x4_t vmax4(f32x4_t a, f32x4_t b) {
    f32x4_t r;
    r[0] = fmaxf(a[0], b[0]); r[1] = fmaxf(a[1], b[1]);
    r[2] = fmaxf(a[2], b[2]); r[3] = fmaxf(a[3], b[3]);
    return r;
}

// ---------------- pre-pass: K -> frag-major bf16 image ----------------
// chunk(tile, f, lane) [16B] = K[tile*64 + (f&3)*16 + (lane&15)]
//                               [(f>>2)*32 + (lane>>4)*8 .. +7]
// Main kernel reads kf[f] = img[tile*1024 + f*64 + lane] -> fully coalesced 1KB/instr.
__global__ __launch_bounds__(256)
void prep_k(const float* __restrict__ k, __bf16* __restrict__ wk)
{
    const int c0 = (blockIdx.x * 256 + threadIdx.x) * 4;   // 16B-chunk index
    #pragma unroll
    for (int i = 0; i < 4; ++i) {
        const int c    = c0 + i;
        const int tile = c >> 10;            // 1024 chunks per 16KB tile
        const int idx  = c & 1023;
        const int f    = idx >> 6;
        const int ln   = idx & 63;
        const int row  = (f & 3) * 16 + (ln & 15);
        const int col  = (f >> 2) * 32 + (ln >> 4) * 8;
        const float* src = k + (((size_t)(tile * 64 + row)) << 7) + col;
        float4 a = ((const float4*)src)[0];
        float4 b = ((const float4*)src)[1];
        bf16x8_t bb;
        bb[0] = (__bf16)a.x; bb[1] = (__bf16)a.y; bb[2] = (__bf16)a.z; bb[3] = (__bf16)a.w;
        bb[4] = (__bf16)b.x; bb[5] = (__bf16)b.y; bb[6] = (__bf16)b.z; bb[7] = (__bf16)b.w;
        *(bf16x8_t*)((char*)wk + (size_t)c * 16) = bb;
    }
}

// ---------------- pre-pass: V -> frag-major V^T bf16 image ----------------
// chunk(tile, f, lane) [16B] = V^T frag: d = (f&7)*16 + (lane&15),
//   value[e] = V[tile*64 + (f>>3)*32 + (lane>>4)*8 + e][d]
__global__ __launch_bounds__(256)
void prep_v(const float* __restrict__ v, __bf16* __restrict__ wv)
{
    __shared__ __bf16 lt[64 * 132];          // staged tile [k][d], padded
    const int tile = blockIdx.x;
    const int tid  = threadIdx.x;
    #pragma unroll
    for (int i = 0; i < 8; ++i) {
        int idx = tid + i * 256;             // 0..2047 float4s
        int r = idx >> 5, cc = idx & 31;
        float4 val = ((const float4*)(v + (((size_t)(tile * 64 + r)) << 7)))[cc];
        bf16x4_t bb;
        bb[0] = (__bf16)val.x; bb[1] = (__bf16)val.y;
        bb[2] = (__bf16)val.z; bb[3] = (__bf16)val.w;
        *(bf16x4_t*)&lt[r * 132 + cc * 4] = bb;
    }
    __syncthreads();
    #pragma unroll
    for (int i = 0; i < 4; ++i) {
        int idx = tid * 4 + i;               // 0..1023 chunk within tile
        int f   = idx >> 6;
        int ln  = idx & 63;
        int d   = (f & 7) * 16 + (ln & 15);
        int kidx = (f >> 3) * 32 + (ln >> 4) * 8;
        bf16x8_t bb;
        #pragma unroll
        for (int z = 0; z < 8; ++z) bb[z] = lt[(kidx + z) * 132 + d];
        *(bf16x8_t*)((char*)wv + (size_t)tile * 16384 + (size_t)idx * 16) = bb;
    }
}

// ---------------- main kernel: reg-resident K/V fragments, ZERO k-loop barriers ----
// K/V A-operands are wave-invariant -> each wave holds its own copy in VGPRs
// (64+64 regs, cap 256 via launch_bounds(256,1); LDS caps occupancy at 2 waves/SIMD
// anyway). Loads for tile j+1 issue right after tile j's operands are consumed by
// MFMA (in-order issue -> WAR safe); compiler places counted vmcnt before first use
// -> ~400cy slack, no vmcnt(0) drain, no s_barrier, no LDS staging, no swizzle.
__global__ __launch_bounds__(256, 1)
void fa_fwd(const float* __restrict__ q, const __bf16* __restrict__ wk,
            const __bf16* __restrict__ wv, float* __restrict__ out)
{
    // 512 blocks: q-tile pair {g, 63-g} -> 66 iters each (R0-proven balance).
    const int L = blockIdx.x;
    const int h = L & 15;
    const int g = L >> 4;
    const int qts[2] = { g, 63 - g };

    const int tid  = threadIdx.x;
    const int wave = tid >> 6;
    const int lane = tid & 63;
    const int l16  = lane & 15;
    const int quad = lane >> 4;
    const int rK   = tid >> 5;
    const int c4   = tid & 31;

    // smem: [q_s 17408 (prologue) / os 34816 (epilogue) overlay][pT 9216] = 44032 B.
    // pT region is disjoint from q_s/os -> no barrier needed between qf reads and
    // pT writes; epilogue os writes don't touch pT.
    __shared__ __align__(16) char smem[44032];
    unsigned short* q_s  = (unsigned short*)smem;
    unsigned short* pT_s = (unsigned short*)(smem + 34816);
    float* os = (float*)smem;

    const float* qh = q + (size_t)h * SS * DHD;
    const bf16x8_t* kh8 = (const bf16x8_t*)wk + (size_t)h * 64 * 1024 + lane;
    const bf16x8_t* vh8 = (const bf16x8_t*)wv + (size_t)h * 64 * 1024 + lane;

    bf16x8_t kf[16];   // K(j) frags: kf[kc*4+mt]
    bf16x8_t vf[16];   // V^T(j) frags: vf[kc*8+mt]
    auto ldk = [&](int j) {
        const bf16x8_t* p = kh8 + (size_t)j * 1024;
        #pragma unroll
        for (int f = 0; f < 16; ++f) kf[f] = p[f * 64];
    };
    auto ldv = [&](int j) {
        const bf16x8_t* p = vh8 + (size_t)j * 1024;
        #pragma unroll
        for (int f = 0; f < 16; ++f) vf[f] = p[f * 64];
    };

    // 1/sqrt(128) * log2(e): softmax in exp2 domain.
    const float scale = 0.088388347648318447f * 1.4426950408889634f;

    for (int t = 0; t < 2; ++t) {
        const int qt = qts[t];
        __syncthreads();               // prev tile's os reads done before q_s overwrite
        ldk(0);                        // prime tile 0; latency hides under Q staging
        ldv(0);

        // ---- stage Q (scale folded) ----
        #pragma unroll
        for (int i = 0; i < 8; ++i) {
            int idx = tid + i * 256;
            int r   = idx >> 5;
            int cc  = idx & 31;
            float4 val = ((const float4*)(qh + (size_t)(qt * BR + r) * DHD))[cc];
            bf16x4_t bb;
            bb[0] = (__bf16)(val.x * scale); bb[1] = (__bf16)(val.y * scale);
            bb[2] = (__bf16)(val.z * scale); bb[3] = (__bf16)(val.w * scale);
            *(bf16x4_t*)&q_s[r * LDQS + cc * 4] = bb;
        }
        __syncthreads();

        // ---- Q B-fragments (n-dim = wave's 16 q rows) ----
        bf16x8_t qf[4];
        #pragma unroll
        for (int kc = 0; kc < 4; ++kc)
            qf[kc] = *(const bf16x8_t*)
                &q_s[(wave * 16 + l16) * LDQS + kc * 32 + quad * 8];

        f32x4_t oacc[8];               // O^T: row=d (8 m-tiles), col=q=l16
        #pragma unroll
        for (int mt = 0; mt < 8; ++mt) oacc[mt] = (f32x4_t)(0.0f);
        float mi = -INFINITY, li = 0.0f;
        const int q_local = wave * 16 + l16;

        for (int j = 0; j <= qt; ++j) {
            // ---- S^T = K Q^T from registers ----
            f32x4_t sa[4];
            #pragma unroll
            for (int mt = 0; mt < 4; ++mt) sa[mt] = (f32x4_t)(0.0f);
            __builtin_amdgcn_s_setprio(1);
            #pragma unroll
            for (int kc = 0; kc < 4; ++kc)
                #pragma unroll
                for (int mt = 0; mt < 4; ++mt)
                    sa[mt] = __builtin_amdgcn_mfma_f32_16x16x32_bf16(
                        kf[kc * 4 + mt], qf[kc], sa[mt], 0, 0, 0);
            __builtin_amdgcn_s_setprio(0);
            if (j < qt) ldk(j + 1);    // refill kf after last read (WAR-safe in-order)

            // ---- causal mask (diag tile only) ----
            if (j == qt) {
                #pragma unroll
                for (int mt = 0; mt < 4; ++mt)
                    #pragma unroll
                    for (int r = 0; r < 4; ++r)
                        if (mt * 16 + quad * 4 + r > q_local) sa[mt][r] = -INFINITY;
            }

            // ---- online softmax (exp2 domain, T13 skip-vote, no common-path shfl) ----
            f32x4_t mv = vmax4(vmax4(sa[0], sa[1]), vmax4(sa[2], sa[3]));
            float mxl = fmaxf(fmaxf(mv[0], mv[1]), fmaxf(mv[2], mv[3]));
            const bool skip = __all((int)(mxl <= mi + 8.0f)) != 0;
            float mnew = mi;
            if (!skip) {
                float mr = fmaxf(mxl, __shfl_xor(mxl, 16));
                mr = fmaxf(mr, __shfl_xor(mr, 32));
                mnew = fmaxf(mi, mr);
                float a = __builtin_amdgcn_exp2f(mi - mnew);
                mi = mnew;
                li *= a;
                #pragma unroll
                for (int mt = 0; mt < 8; ++mt) {
                    oacc[mt][0] *= a; oacc[mt][1] *= a;
                    oacc[mt][2] *= a; oacc[mt][3] *= a;
                }
            }
            bf16x4_t pkv[4];
            #pragma unroll
            for (int mt = 0; mt < 4; ++mt) {
                #pragma unroll
                for (int r = 0; r < 4; ++r)
                    sa[mt][r] = __builtin_amdgcn_exp2f(sa[mt][r] - mnew);
                pkv[mt][0] = (__bf16)sa[mt][0]; pkv[mt][1] = (__bf16)sa[mt][1];
                pkv[mt][2] = (__bf16)sa[mt][2]; pkv[mt][3] = (__bf16)sa[mt][3];
                *(bf16x4_t*)&pT_s[q_local * LDPT + mt * 16 + quad * 4] = pkv[mt];
            }
            f32x4_t sv = sa[0] + sa[1] + sa[2] + sa[3];
            li += (sv[0] + sv[1]) + (sv[2] + sv[3]);

            // ---- O^T += V^T P^T from registers (P via wave-local pT round-trip) ----
            __builtin_amdgcn_s_setprio(1);
            #pragma unroll
            for (int kc = 0; kc < 2; ++kc) {
                bf16x8_t pb = *(const bf16x8_t*)
                    &pT_s[q_local * LDPT + kc * 32 + quad * 8];
                #pragma unroll
                for (int mt = 0; mt < 8; ++mt)
                    oacc[mt] = __builtin_amdgcn_mfma_f32_16x16x32_bf16(
                        vf[kc * 8 + mt], pb, oacc[mt], 0, 0, 0);
            }
            __builtin_amdgcn_s_setprio(0);
            if (j < qt) ldv(j + 1);    // refill vf after last read
        }

        // ---- li quad-reduction: 2 shfls once per tile ----
        li += __shfl_xor(li, 16);
        li += __shfl_xor(li, 32);

        // ---- epilogue: O^T -> LDS overlay -> coalesced fp32 store ----
        __syncthreads();
        float inv = 1.0f / li;
        #pragma unroll
        for (int mt = 0; mt < 8; ++mt)
            #pragma unroll
            for (int r = 0; r < 4; ++r)
                os[(wave * 16 + l16) * LDOS + mt * 16 + quad * 4 + r] = oacc[mt][r] * inv;
        __syncthreads();
        #pragma unroll
        for (int p = 0; p < 8; ++p) {
            int row = p * 8 + rK;
            float4 f4 = *(const float4*)&os[row * LDOS + c4 * 4];
            *(float4*)&out[(size_t)(qt * BR + row) * DM + h * DHD + c4 * 4] = f4;
        }
    }
}

// ---------------- fallback (R0-proven, 183 us) if workspace too small ----------------
__global__ __launch_bounds__(256, 2)
void fa_fwd_fb(const float* __restrict__ q, const float* __restrict__ k,
               const float* __restrict__ v, float* __restrict__ out)
{
    const int L = blockIdx.x;
    const int h = L & 15;
    const int g = L >> 4;
    const int qts[2] = { g, 63 - g };

    const int tid  = threadIdx.x;
    const int wave = tid >> 6;
    const int lane = tid & 63;
    const int l16  = lane & 15;
    const int quad = lane >> 4;
    const int rK   = tid >> 5;
    const int c4   = tid & 31;
    const int dbase = (wave & 1) * 64;
    const int rbase = (wave >> 1) * 32;

    __shared__ __align__(16) char smem[63488];
    unsigned short* qp_s = (unsigned short*)smem;
    unsigned short* k_s  = (unsigned short*)(smem + 18432);
    unsigned short* vt_s = (unsigned short*)(smem + 36864);
    unsigned short* pT_s = (unsigned short*)(smem + 54272);
    float* os = (float*)smem;

    const size_t hoff = (size_t)h * SS * DHD;
    const float* qh = q + hoff;
    const float* kh = k + hoff;
    const float* vh = v + hoff;

    float4 kreg[8];
    float  vreg[8][4];
    auto issue = [&](int j) {
        const float* kb = kh + (size_t)j * BC * DHD;
        #pragma unroll
        for (int i = 0; i < 8; ++i)
            kreg[i] = ((const float4*)(kb + (size_t)(rK + i * 8) * DHD))[c4];
        const float* vb = vh + (size_t)j * BC * DHD + dbase + lane;
        #pragma unroll
        for (int p = 0; p < 8; ++p) {
            const float* vp = vb + (size_t)(rbase + p * 4) * DHD;
            vreg[p][0] = vp[0];
            vreg[p][1] = vp[DHD];
            vreg[p][2] = vp[2 * DHD];
            vreg[p][3] = vp[3 * DHD];
        }
    };

    const float scale = 0.088388347648318447f;
    issue(0);

    for (int t = 0; t < 2; ++t) {
        const int qt = qts[t];
        __syncthreads();
        #pragma unroll
        for (int i = 0; i < 8; ++i) {
            int idx = tid + i * 256;
            int r   = idx >> 5;
            int cc  = idx & 31;
            float4 val = ((const float4*)(qh + (size_t)(qt * BR + r) * DHD))[cc];
            bf16x4_t bb;
            bb[0] = (__bf16)(val.x * scale); bb[1] = (__bf16)(val.y * scale);
            bb[2] = (__bf16)(val.z * scale); bb[3] = (__bf16)(val.w * scale);
            *(bf16x4_t*)&qp_s[r * LDQ + cc * 4] = bb;
        }
        __syncthreads();

        bf16x8_t qf[4];
        #pragma unroll
        for (int kc = 0; kc < 4; ++kc)
            qf[kc] = *(const bf16x8_t*)
                &qp_s[(wave * 16 + l16) * LDQ + kc * 32 + quad * 8];

        f32x4_t oacc[8];
        #pragma unroll
        for (int mt = 0; mt < 8; ++mt) oacc[mt] = (f32x4_t)(0.0f);
        float mi = -INFINITY, li = 0.0f;
        const int q_local = wave * 16 + l16;

        for (int j = 0; j <= qt; ++j) {
            BAR();
            #pragma unroll
            for (int i = 0; i < 8; ++i) {
                bf16x4_t bb;
                bb[0] = (__bf16)kreg[i].x; bb[1] = (__bf16)kreg[i].y;
                bb[2] = (__bf16)kreg[i].z; bb[3] = (__bf16)kreg[i].w;
                *(bf16x4_t*)&k_s[(rK + i * 8) * LDQ + c4 * 4] = bb;
            }
            #pragma unroll
            for (int p = 0; p < 8; ++p) {
                bf16x4_t bb;
                bb[0] = (__bf16)vreg[p][0]; bb[1] = (__bf16)vreg[p][1];
                bb[2] = (__bf16)vreg[p][2]; bb[3] = (__bf16)vreg[p][3];
                *(bf16x4_t*)&vt_s[(dbase + lane) * LDV + rbase + p * 4] = bb;
            }
            if (j < qt)      issue(j + 1);
            else if (t == 0) issue(0);
            BAR();

            f32x4_t sa[4];
            #pragma unroll
            for (int mt = 0; mt < 4; ++mt) sa[mt] = (f32x4_t)(0.0f);
            #pragma unroll
            for (int kc = 0; kc < 4; ++kc)
                #pragma unroll
                for (int mt = 0; mt < 4; ++mt) {
                    bf16x8_t kf = *(const bf16x8_t*)
                        &k_s[(mt * 16 + l16) * LDQ + kc * 32 + quad * 8];
                    sa[mt] = __builtin_amdgcn_mfma_f32_16x16x32_bf16(kf, qf[kc], sa[mt], 0, 0, 0);
                }

            if (j == qt) {
                #pragma unroll
                for (int mt = 0; mt < 4; ++mt)
                    #pragma unroll
                    for (int r = 0; r < 4; ++r)
                        if (mt * 16 + quad * 4 + r > q_local) sa[mt][r] = -INFINITY;
            }

            f32x4_t mv = vmax4(vmax4(sa[0], sa[1]), vmax4(sa[2], sa[3]));
            float mx = fmaxf(fmaxf(mv[0], mv[1]), fmaxf(mv[2], mv[3]));
            mx = fmaxf(mx, __shfl_xor(mx, 16));
            mx = fmaxf(mx, __shfl_xor(mx, 32));
            float mnew = fmaxf(mi, mx);
            float a = __expf(mi - mnew);
            mi = mnew;
            bf16x4_t pkv[4];
            #pragma unroll
            for (int mt = 0; mt < 4; ++mt) {
                #pragma unroll
                for (int r = 0; r < 4; ++r) sa[mt][r] = __expf(sa[mt][r] - mnew);
                pkv[mt][0] = (__bf16)sa[mt][0]; pkv[mt][1] = (__bf16)sa[mt][1];
                pkv[mt][2] = (__bf16)sa[mt][2]; pkv[mt][3] = (__bf16)sa[mt][3];
            }
            f32x4_t sv = sa[0] + sa[1] + sa[2] + sa[3];
            float rs = (sv[0] + sv[1]) + (sv[2] + sv[3]);
            rs += __shfl_xor(rs, 16);
            rs += __shfl_xor(rs, 32);
            li = li * a + rs;

            #pragma unroll
            for (int mt = 0; mt < 4; ++mt)
                *(bf16x4_t*)&pT_s[(wave * 16 + l16) * LDPT + mt * 16 + quad * 4] = pkv[mt];

            #pragma unroll
            for (int mt = 0; mt < 8; ++mt) {
                oacc[mt][0] *= a; oacc[mt][1] *= a;
                oacc[mt][2] *= a; oacc[mt][3] *= a;
            }

            #pragma unroll
            for (int kc = 0; kc < 2; ++kc) {
                bf16x8_t pb = *(const bf16x8_t*)
                    &pT_s[(wave * 16 + l16) * LDPT + kc * 32 + quad * 8];
                #pragma unroll
                for (int mt = 0; mt < 8; ++mt) {
                    bf16x4_t vlo = *(const bf16x4_t*)
                        &vt_s[(mt * 16 + l16) * LDV + kc * 32 + quad * 8];
                    bf16x4_t vhi = *(const bf16x4_t*)
                        &vt_s[(mt * 16 + l16) * LDV + kc * 32 + quad * 8 + 4];
                    bf16x8_t vf = __builtin_shufflevector(vlo, vhi, 0,1,2,3,4,5,6,7);
                    oacc[mt] = __builtin_amdgcn_mfma_f32_16x16x32_bf16(vf, pb, oacc[mt], 0, 0, 0);
                }
            }
        }

        __syncthreads();
        float inv = 1.0f / li;
        #pragma unroll
        for (int mt = 0; mt < 8; ++mt)
            #pragma unroll
            for (int r = 0; r < 4; ++r)
                os[(wave * 16 + l16) * LDOS + mt * 16 + quad * 4 + r] = oacc[mt][r] * inv;
        __syncthreads();
        #pragma unroll
        for (int p = 0; p < 8; ++p) {
            int row = p * 8 + rK;
            float4 f4 = *(const float4*)&os[row * LDOS + c4 * 4];
            *(float4*)&out[(size_t)(qt * BR + row) * DM + h * DHD + c4 * 4] = f4;
        }
    }
}

extern "C" void kernel_launch(void* const* d_in, const int* in_sizes, int n_in,
                              void* d_out, int out_size, void* d_ws, size_t ws_size,
                              hipStream_t stream) {
    const float* q = (const float*)d_in[0];
    const float* k = (const float*)d_in[1];
    const float* v = (const float*)d_in[2];
    float* out = (float*)d_out;
    if (d_ws != nullptr && ws_size >= (size_t)33554432) {
        __bf16* wk = (__bf16*)d_ws;
        __bf16* wv = (__bf16*)((char*)d_ws + 16777216);
        prep_k<<<dim3(1024), dim3(256), 0, stream>>>(k, wk);
        prep_v<<<dim3(1024), dim3(256), 0, stream>>>(v, wv);
        fa_fwd<<<dim3((SS / BR / 2) * HH), dim3(256), 0, stream>>>(q, wk, wv, out);
    } else {
        fa_fwd_fb<<<dim3((SS / BR / 2) * HH), dim3(256), 0, stream>>>(q, k, v, out);
    }
}

// Round 11
// 262.669 us; speedup vs baseline: 1.1541x; 1.1541x over previous
//
#include <hip/hip_runtime.h>

#define HH 16
#define SS 4096
#define DHD 128
#define BR 64         // q rows per block (16 per wave)
#define BC 64         // k/v rows per tile
#define LDQS 136      // bf16/row for Q staging (prologue only)
#define LDQ 144       // fallback kernel k_s stride (R0-measured-good)
#define LDV 68        // fallback kernel vt_s stride
#define LDPT 72       // bf16/row for pT_s: 144B (16B-aligned)
#define LDOS 136      // f32/row for epilogue overlay
#define DM  (HH * DHD)
#define KTILE 16384

typedef __bf16 bf16x8_t __attribute__((ext_vector_type(8)));
typedef __bf16 bf16x4_t __attribute__((ext_vector_type(4)));
typedef float  f32x4_t  __attribute__((ext_vector_type(4)));

// lgkm-drain barrier (LDS-only sync; leaves global loads in flight)
#define BAR()  asm volatile("s_waitcnt lgkmcnt(0)\n\ts_barrier" ::: "memory")
// vm-drain barrier (global_load_lds landed; issued a full iteration earlier)
#define BARV() asm volatile("s_waitcnt vmcnt(0)\n\ts_barrier" ::: "memory")

typedef __attribute__((address_space(1))) const void gas_t;
typedef __attribute__((address_space(3))) void las_t;
__device__ __forceinline__ void gl16(const void* g, void* l) {
    __builtin_amdgcn_global_load_lds((gas_t*)g, (las_t*)l, 16, 0, 0);
}

__device__ __forceinline__ f32x4_t vmax4(f32x4_t a, f32x4_t b) {
    f32x4_t r;
    r[0] = fmaxf(a[0], b[0]); r[1] = fmaxf(a[1], b[1]);
    r[2] = fmaxf(a[2], b[2]); r[3] = fmaxf(a[3], b[3]);
    return r;
}

// ---------------- pre-pass: K -> frag-major bf16 image (R10-verified) ----------------
// chunk(tile, f, lane) [16B] = K[tile*64 + (f&3)*16 + (lane&15)]
//                               [(f>>2)*32 + (lane>>4)*8 .. +7]
// fa_fwd reads kf[f] = lds[f*1024 + lane*16] -> lane-linear ds_read_b128,
// conflict-free by construction, zero per-read address math.
__global__ __launch_bounds__(256)
void prep_k(const float* __restrict__ k, __bf16* __restrict__ wk)
{
    const int c0 = (blockIdx.x * 256 + threadIdx.x) * 4;   // 16B-chunk index
    #pragma unroll
    for (int i = 0; i < 4; ++i) {
        const int c    = c0 + i;
        const int tile = c >> 10;            // 1024 chunks per 16KB tile
        const int idx  = c & 1023;
        const int f    = idx >> 6;
        const int ln   = idx & 63;
        const int row  = (f & 3) * 16 + (ln & 15);
        const int col  = (f >> 2) * 32 + (ln >> 4) * 8;
        const float* src = k + (((size_t)(tile * 64 + row)) << 7) + col;
        float4 a = ((const float4*)src)[0];
        float4 b = ((const float4*)src)[1];
        bf16x8_t bb;
        bb[0] = (__bf16)a.x; bb[1] = (__bf16)a.y; bb[2] = (__bf16)a.z; bb[3] = (__bf16)a.w;
        bb[4] = (__bf16)b.x; bb[5] = (__bf16)b.y; bb[6] = (__bf16)b.z; bb[7] = (__bf16)b.w;
        *(bf16x8_t*)((char*)wk + (size_t)c * 16) = bb;
    }
}

// ---------------- pre-pass: V -> frag-major V^T bf16 image (R10-verified) ----------------
// chunk(tile, f, lane) [16B] = V^T frag: d = (f&7)*16 + (lane&15),
//   value[e] = V[tile*64 + (f>>3)*32 + (lane>>4)*8 + e][d]
__global__ __launch_bounds__(256)
void prep_v(const float* __restrict__ v, __bf16* __restrict__ wv)
{
    __shared__ __bf16 lt[64 * 132];          // staged tile [k][d], padded
    const int tile = blockIdx.x;
    const int tid  = threadIdx.x;
    #pragma unroll
    for (int i = 0; i < 8; ++i) {
        int idx = tid + i * 256;             // 0..2047 float4s
        int r = idx >> 5, cc = idx & 31;
        float4 val = ((const float4*)(v + (((size_t)(tile * 64 + r)) << 7)))[cc];
        bf16x4_t bb;
        bb[0] = (__bf16)val.x; bb[1] = (__bf16)val.y;
        bb[2] = (__bf16)val.z; bb[3] = (__bf16)val.w;
        *(bf16x4_t*)&lt[r * 132 + cc * 4] = bb;
    }
    __syncthreads();
    #pragma unroll
    for (int i = 0; i < 4; ++i) {
        int idx = tid * 4 + i;               // 0..1023 chunk within tile
        int f   = idx >> 6;
        int ln  = idx & 63;
        int d   = (f & 7) * 16 + (ln & 15);
        int kidx = (f >> 3) * 32 + (ln >> 4) * 8;
        bf16x8_t bb;
        #pragma unroll
        for (int z = 0; z < 8; ++z) bb[z] = lt[(kidx + z) * 132 + d];
        *(bf16x8_t*)((char*)wv + (size_t)tile * 16384 + (size_t)idx * 16) = bb;
    }
}

// ---------------- main kernel: R9 schedule + frag-major linear LDS reads ----------------
// Iter j: issue DMA K[j+2]/V[j+1]; QK(j+1) MFMAs overlap softmax(j)+PV(j).
// K staged distance-2 into kb[j&1], V distance-1. One vmcnt(0)+barrier per iter.
// Operand reads are lane-linear b128 (frag-major image) -> conflict-free, no addr math.
__global__ __launch_bounds__(256, 2)
void fa_fwd(const float* __restrict__ q, const __bf16* __restrict__ wk,
            const __bf16* __restrict__ wv, float* __restrict__ out)
{
    // 512 blocks: q-tile pair {g, 63-g} -> 66 iters each (R0-proven balance).
    const int L = blockIdx.x;
    const int h = L & 15;
    const int g = L >> 4;
    const int qts[2] = { g, 63 - g };

    const int tid  = threadIdx.x;
    const int wave = tid >> 6;
    const int lane = tid & 63;
    const int l16  = lane & 15;
    const int quad = lane >> 4;
    const int rK   = tid >> 5;
    const int c4   = tid & 31;

    // smem: [kbuf0 16384][kbuf1 16384][vbuf0 16384][vbuf1 16384][pT 9216] = 74752.
    // Q staging (17408 B) overlays vbuf0+ (consumed to regs before first stageV).
    // Epilogue os overlay (34816 B) over kbufs.
    __shared__ __align__(16) char smem[74752];
    unsigned short* pT_s = (unsigned short*)(smem + 65536);
    unsigned short* q_s  = (unsigned short*)(smem + 32768);
    float* os = (float*)smem;

    const float* qh = q + (size_t)h * SS * DHD;

    auto stageK = [&](int j, int b) {
        const char* gk = (const char*)wk + ((size_t)(h * 64 + j)) * KTILE + wave * 4096 + lane * 16;
        char* lk = smem + b * KTILE + wave * 4096;          // wave-uniform dest
        #pragma unroll
        for (int c2 = 0; c2 < 4; ++c2) gl16(gk + c2 * 1024, lk + c2 * 1024);
    };
    auto stageV = [&](int j, int b) {
        const char* gv = (const char*)wv + ((size_t)(h * 64 + j)) * KTILE + wave * 4096 + lane * 16;
        char* lv = smem + 32768 + b * KTILE + wave * 4096;
        #pragma unroll
        for (int c2 = 0; c2 < 4; ++c2) gl16(gv + c2 * 1024, lv + c2 * 1024);
    };

    // 1/sqrt(128) * log2(e): softmax in exp2 domain.
    const float scale = 0.088388347648318447f * 1.4426950408889634f;

#define ITER(SC, SN) do {                                                     \
    if (j + 2 <= qt) stageK(j + 2, j & 1);                                    \
    if (j + 1 <= qt) stageV(j + 1, (j + 1) & 1);                              \
    if (j < qt) {                                                             \
        const char* kbp = smem + ((j + 1) & 1) * KTILE + lane * 16;           \
        __builtin_amdgcn_s_setprio(1);                                        \
        _Pragma("unroll")                                                     \
        for (int mt = 0; mt < 4; ++mt)                                        \
            SN[mt] = __builtin_amdgcn_mfma_f32_16x16x32_bf16(                 \
                *(const bf16x8_t*)(kbp + mt * 1024), qf[0],                   \
                (f32x4_t)(0.0f), 0, 0, 0);                                    \
        _Pragma("unroll")                                                     \
        for (int kc = 1; kc < 4; ++kc)                                        \
            _Pragma("unroll")                                                 \
            for (int mt = 0; mt < 4; ++mt)                                    \
                SN[mt] = __builtin_amdgcn_mfma_f32_16x16x32_bf16(             \
                    *(const bf16x8_t*)(kbp + (kc * 4 + mt) * 1024), qf[kc],   \
                    SN[mt], 0, 0, 0);                                         \
        __builtin_amdgcn_s_setprio(0);                                        \
    }                                                                         \
    if (j == qt) {                                                            \
        _Pragma("unroll")                                                     \
        for (int mt = 0; mt < 4; ++mt)                                        \
            _Pragma("unroll")                                                 \
            for (int r = 0; r < 4; ++r)                                       \
                if (mt * 16 + quad * 4 + r > q_local) SC[mt][r] = -INFINITY;  \
    }                                                                         \
    f32x4_t mv = vmax4(vmax4(SC[0], SC[1]), vmax4(SC[2], SC[3]));             \
    float mxl = fmaxf(fmaxf(mv[0], mv[1]), fmaxf(mv[2], mv[3]));              \
    const bool skip = __all((int)(mxl <= mi + 8.0f)) != 0;                    \
    float mnew = mi;                                                          \
    if (!skip) {                                                              \
        float mr = fmaxf(mxl, __shfl_xor(mxl, 16));                           \
        mr = fmaxf(mr, __shfl_xor(mr, 32));                                   \
        mnew = fmaxf(mi, mr);                                                 \
        float a = __builtin_amdgcn_exp2f(mi - mnew);                          \
        mi = mnew;                                                            \
        li *= a;                                                              \
        _Pragma("unroll")                                                     \
        for (int mt = 0; mt < 8; ++mt) {                                      \
            oacc[mt][0] *= a; oacc[mt][1] *= a;                               \
            oacc[mt][2] *= a; oacc[mt][3] *= a;                               \
        }                                                                     \
    }                                                                         \
    bf16x4_t pkv[4];                                                          \
    _Pragma("unroll")                                                         \
    for (int mt = 0; mt < 4; ++mt) {                                          \
        _Pragma("unroll")                                                     \
        for (int r = 0; r < 4; ++r)                                           \
            SC[mt][r] = __builtin_amdgcn_exp2f(SC[mt][r] - mnew);             \
        pkv[mt][0] = (__bf16)SC[mt][0]; pkv[mt][1] = (__bf16)SC[mt][1];       \
        pkv[mt][2] = (__bf16)SC[mt][2]; pkv[mt][3] = (__bf16)SC[mt][3];       \
        *(bf16x4_t*)&pT_s[q_local * LDPT + mt * 16 + quad * 4] = pkv[mt];     \
    }                                                                         \
    f32x4_t sv = SC[0] + SC[1] + SC[2] + SC[3];                               \
    li += (sv[0] + sv[1]) + (sv[2] + sv[3]);                                  \
    {                                                                         \
        const char* vbp = smem + 32768 + (j & 1) * KTILE + lane * 16;         \
        __builtin_amdgcn_s_setprio(1);                                        \
        _Pragma("unroll")                                                     \
        for (int kc = 0; kc < 2; ++kc) {                                      \
            bf16x8_t pb = *(const bf16x8_t*)&pT_s[q_local * LDPT + kc * 32 + quad * 8]; \
            _Pragma("unroll")                                                 \
            for (int mt = 0; mt < 8; ++mt)                                    \
                oacc[mt] = __builtin_amdgcn_mfma_f32_16x16x32_bf16(           \
                    *(const bf16x8_t*)(vbp + (kc * 8 + mt) * 1024), pb,       \
                    oacc[mt], 0, 0, 0);                                       \
        }                                                                     \
        __builtin_amdgcn_s_setprio(0);                                        \
    }                                                                         \
    BARV();                                                                   \
} while (0)

    for (int t = 0; t < 2; ++t) {
        const int qt = qts[t];
        __syncthreads();               // prev tile's os/LDS reads done
        // ---- issue K0/K1 DMA early (latency covered by Q staging) ----
        stageK(0, 0);
        stageK(1, 1);
        // ---- stage Q (scale folded) into q_s overlay ----
        #pragma unroll
        for (int i = 0; i < 8; ++i) {
            int idx = tid + i * 256;
            int r   = idx >> 5;
            int cc  = idx & 31;
            float4 val = ((const float4*)(qh + (size_t)(qt * BR + r) * DHD))[cc];
            bf16x4_t bb;
            bb[0] = (__bf16)(val.x * scale); bb[1] = (__bf16)(val.y * scale);
            bb[2] = (__bf16)(val.z * scale); bb[3] = (__bf16)(val.w * scale);
            *(bf16x4_t*)&q_s[r * LDQS + cc * 4] = bb;
        }
        __syncthreads();

        // ---- Q B-fragments ----
        bf16x8_t qf[4];
        #pragma unroll
        for (int kc = 0; kc < 4; ++kc)
            qf[kc] = *(const bf16x8_t*)
                &q_s[(wave * 16 + l16) * LDQS + kc * 32 + quad * 8];
        BAR();                          // q_s reads retired before V0 DMA overwrites
        stageV(0, 0);

        f32x4_t oacc[8];
        #pragma unroll
        for (int mt = 0; mt < 8; ++mt) oacc[mt] = (f32x4_t)(0.0f);
        float mi = -INFINITY, li = 0.0f;
        const int q_local = wave * 16 + l16;

        BARV();                         // K0, K1, V0 landed (all waves)

        // ---- prologue: QK(0) -> sA ----
        f32x4_t sA[4], sB[4];
        {
            const char* kbp = smem + lane * 16;   // kb0
            __builtin_amdgcn_s_setprio(1);
            #pragma unroll
            for (int mt = 0; mt < 4; ++mt)
                sA[mt] = __builtin_amdgcn_mfma_f32_16x16x32_bf16(
                    *(const bf16x8_t*)(kbp + mt * 1024), qf[0],
                    (f32x4_t)(0.0f), 0, 0, 0);
            #pragma unroll
            for (int kc = 1; kc < 4; ++kc)
                #pragma unroll
                for (int mt = 0; mt < 4; ++mt)
                    sA[mt] = __builtin_amdgcn_mfma_f32_16x16x32_bf16(
                        *(const bf16x8_t*)(kbp + (kc * 4 + mt) * 1024), qf[kc],
                        sA[mt], 0, 0, 0);
            __builtin_amdgcn_s_setprio(0);
        }

        int j = 0;
        for (;;) {
            ITER(sA, sB);
            if (j == qt) break; ++j;
            ITER(sB, sA);
            if (j == qt) break; ++j;
        }

        // ---- li quad-reduction (deferred from the loop): 2 shfls once ----
        li += __shfl_xor(li, 16);
        li += __shfl_xor(li, 32);

        // ---- epilogue: O^T -> LDS overlay -> coalesced fp32 store ----
        __syncthreads();
        float inv = 1.0f / li;
        #pragma unroll
        for (int mt = 0; mt < 8; ++mt)
            #pragma unroll
            for (int r = 0; r < 4; ++r)
                os[(wave * 16 + l16) * LDOS + mt * 16 + quad * 4 + r] = oacc[mt][r] * inv;
        __syncthreads();
        #pragma unroll
        for (int p = 0; p < 8; ++p) {
            int row = p * 8 + rK;
            float4 f4 = *(const float4*)&os[row * LDOS + c4 * 4];
            *(float4*)&out[(size_t)(qt * BR + row) * DM + h * DHD + c4 * 4] = f4;
        }
    }
#undef ITER
}

// ---------------- fallback (R0-proven, 183 us) if workspace too small ----------------
__global__ __launch_bounds__(256, 2)
void fa_fwd_fb(const float* __restrict__ q, const float* __restrict__ k,
               const float* __restrict__ v, float* __restrict__ out)
{
    const int L = blockIdx.x;
    const int h = L & 15;
    const int g = L >> 4;
    const int qts[2] = { g, 63 - g };

    const int tid  = threadIdx.x;
    const int wave = tid >> 6;
    const int lane = tid & 63;
    const int l16  = lane & 15;
    const int quad = lane >> 4;
    const int rK   = tid >> 5;
    const int c4   = tid & 31;
    const int dbase = (wave & 1) * 64;
    const int rbase = (wave >> 1) * 32;

    __shared__ __align__(16) char smem[63488];
    unsigned short* qp_s = (unsigned short*)smem;
    unsigned short* k_s  = (unsigned short*)(smem + 18432);
    unsigned short* vt_s = (unsigned short*)(smem + 36864);
    unsigned short* pT_s = (unsigned short*)(smem + 54272);
    float* os = (float*)smem;

    const size_t hoff = (size_t)h * SS * DHD;
    const float* qh = q + hoff;
    const float* kh = k + hoff;
    const float* vh = v + hoff;

    float4 kreg[8];
    float  vreg[8][4];
    auto issue = [&](int j) {
        const float* kb = kh + (size_t)j * BC * DHD;
        #pragma unroll
        for (int i = 0; i < 8; ++i)
            kreg[i] = ((const float4*)(kb + (size_t)(rK + i * 8) * DHD))[c4];
        const float* vb = vh + (size_t)j * BC * DHD + dbase + lane;
        #pragma unroll
        for (int p = 0; p < 8; ++p) {
            const float* vp = vb + (size_t)(rbase + p * 4) * DHD;
            vreg[p][0] = vp[0];
            vreg[p][1] = vp[DHD];
            vreg[p][2] = vp[2 * DHD];
            vreg[p][3] = vp[3 * DHD];
        }
    };

    const float scale = 0.088388347648318447f;
    issue(0);

    for (int t = 0; t < 2; ++t) {
        const int qt = qts[t];
        __syncthreads();
        #pragma unroll
        for (int i = 0; i < 8; ++i) {
            int idx = tid + i * 256;
            int r   = idx >> 5;
            int cc  = idx & 31;
            float4 val = ((const float4*)(qh + (size_t)(qt * BR + r) * DHD))[cc];
            bf16x4_t bb;
            bb[0] = (__bf16)(val.x * scale); bb[1] = (__bf16)(val.y * scale);
            bb[2] = (__bf16)(val.z * scale); bb[3] = (__bf16)(val.w * scale);
            *(bf16x4_t*)&qp_s[r * LDQ + cc * 4] = bb;
        }
        __syncthreads();

        bf16x8_t qf[4];
        #pragma unroll
        for (int kc = 0; kc < 4; ++kc)
            qf[kc] = *(const bf16x8_t*)
                &qp_s[(wave * 16 + l16) * LDQ + kc * 32 + quad * 8];

        f32x4_t oacc[8];
        #pragma unroll
        for (int mt = 0; mt < 8; ++mt) oacc[mt] = (f32x4_t)(0.0f);
        float mi = -INFINITY, li = 0.0f;
        const int q_local = wave * 16 + l16;

        for (int j = 0; j <= qt; ++j) {
            BAR();
            #pragma unroll
            for (int i = 0; i < 8; ++i) {
                bf16x4_t bb;
                bb[0] = (__bf16)kreg[i].x; bb[1] = (__bf16)kreg[i].y;
                bb[2] = (__bf16)kreg[i].z; bb[3] = (__bf16)kreg[i].w;
                *(bf16x4_t*)&k_s[(rK + i * 8) * LDQ + c4 * 4] = bb;
            }
            #pragma unroll
            for (int p = 0; p < 8; ++p) {
                bf16x4_t bb;
                bb[0] = (__bf16)vreg[p][0]; bb[1] = (__bf16)vreg[p][1];
                bb[2] = (__bf16)vreg[p][2]; bb[3] = (__bf16)vreg[p][3];
                *(bf16x4_t*)&vt_s[(dbase + lane) * LDV + rbase + p * 4] = bb;
            }
            if (j < qt)      issue(j + 1);
            else if (t == 0) issue(0);
            BAR();

            f32x4_t sa[4];
            #pragma unroll
            for (int mt = 0; mt < 4; ++mt) sa[mt] = (f32x4_t)(0.0f);
            #pragma unroll
            for (int kc = 0; kc < 4; ++kc)
                #pragma unroll
                for (int mt = 0; mt < 4; ++mt) {
                    bf16x8_t kf = *(const bf16x8_t*)
                        &k_s[(mt * 16 + l16) * LDQ + kc * 32 + quad * 8];
                    sa[mt] = __builtin_amdgcn_mfma_f32_16x16x32_bf16(kf, qf[kc], sa[mt], 0, 0, 0);
                }

            if (j == qt) {
                #pragma unroll
                for (int mt = 0; mt < 4; ++mt)
                    #pragma unroll
                    for (int r = 0; r < 4; ++r)
                        if (mt * 16 + quad * 4 + r > q_local) sa[mt][r] = -INFINITY;
            }

            f32x4_t mv = vmax4(vmax4(sa[0], sa[1]), vmax4(sa[2], sa[3]));
            float mx = fmaxf(fmaxf(mv[0], mv[1]), fmaxf(mv[2], mv[3]));
            mx = fmaxf(mx, __shfl_xor(mx, 16));
            mx = fmaxf(mx, __shfl_xor(mx, 32));
            float mnew = fmaxf(mi, mx);
            float a = __expf(mi - mnew);
            mi = mnew;
            bf16x4_t pkv[4];
            #pragma unroll
            for (int mt = 0; mt < 4; ++mt) {
                #pragma unroll
                for (int r = 0; r < 4; ++r) sa[mt][r] = __expf(sa[mt][r] - mnew);
                pkv[mt][0] = (__bf16)sa[mt][0]; pkv[mt][1] = (__bf16)sa[mt][1];
                pkv[mt][2] = (__bf16)sa[mt][2]; pkv[mt][3] = (__bf16)sa[mt][3];
            }
            f32x4_t sv = sa[0] + sa[1] + sa[2] + sa[3];
            float rs = (sv[0] + sv[1]) + (sv[2] + sv[3]);
            rs += __shfl_xor(rs, 16);
            rs += __shfl_xor(rs, 32);
            li = li * a + rs;

            #pragma unroll
            for (int mt = 0; mt < 4; ++mt)
                *(bf16x4_t*)&pT_s[(wave * 16 + l16) * LDPT + mt * 16 + quad * 4] = pkv[mt];

            #pragma unroll
            for (int mt = 0; mt < 8; ++mt) {
                oacc[mt][0] *= a; oacc[mt][1] *= a;
                oacc[mt][2] *= a; oacc[mt][3] *= a;
            }

            #pragma unroll
            for (int kc = 0; kc < 2; ++kc) {
                bf16x8_t pb = *(const bf16x8_t*)
                    &pT_s[(wave * 16 + l16) * LDPT + kc * 32 + quad * 8];
                #pragma unroll
                for (int mt = 0; mt < 8; ++mt) {
                    bf16x4_t vlo = *(const bf16x4_t*)
                        &vt_s[(mt * 16 + l16) * LDV + kc * 32 + quad * 8];
                    bf16x4_t vhi = *(const bf16x4_t*)
                        &vt_s[(mt * 16 + l16) * LDV + kc * 32 + quad * 8 + 4];
                    bf16x8_t vf = __builtin_shufflevector(vlo, vhi, 0,1,2,3,4,5,6,7);
                    oacc[mt] = __builtin_amdgcn_mfma_f32_16x16x32_bf16(vf, pb, oacc[mt], 0, 0, 0);
                }
            }
        }

        __syncthreads();
        float inv = 1.0f / li;
        #pragma unroll
        for (int mt = 0; mt < 8; ++mt)
            #pragma unroll
            for (int r = 0; r < 4; ++r)
                os[(wave * 16 + l16) * LDOS + mt * 16 + quad * 4 + r] = oacc[mt][r] * inv;
        __syncthreads();
        #pragma unroll
        for (int p = 0; p < 8; ++p) {
            int row = p * 8 + rK;
            float4 f4 = *(const float4*)&os[row * LDOS + c4 * 4];
            *(float4*)&out[(size_t)(qt * BR + row) * DM + h * DHD + c4 * 4] = f4;
        }
    }
}

extern "C" void kernel_launch(void* const* d_in, const int* in_sizes, int n_in,
                              void* d_out, int out_size, void* d_ws, size_t ws_size,
                              hipStream_t stream) {
    const float* q = (const float*)d_in[0];
    const float* k = (const float*)d_in[1];
    const float* v = (const float*)d_in[2];
    float* out = (float*)d_out;
    if (d_ws != nullptr && ws_size >= (size_t)33554432) {
        __bf16* wk = (__bf16*)d_ws;
        __bf16* wv = (__bf16*)((char*)d_ws + 16777216);
        prep_k<<<dim3(1024), dim3(256), 0, stream>>>(k, wk);
        prep_v<<<dim3(1024), dim3(256), 0, stream>>>(v, wv);
        fa_fwd<<<dim3((SS / BR / 2) * HH), dim3(256), 0, stream>>>(q, wk, wv, out);
    } else {
        fa_fwd_fb<<<dim3((SS / BR / 2) * HH), dim3(256), 0, stream>>>(q, k, v, out);
    }
}